// Round 1
// baseline (1539.517 us; speedup 1.0000x reference)
//
#include <hip/hip_runtime.h>
#include <math.h>

#define NN   100000
#define INF_ 256
#define HID  128
#define OUTF 16
#define NE   1600000

// ---------------------------------------------------------------- degree
__global__ __launch_bounds__(256) void k_deg(const int* __restrict__ dst,
                                             int* __restrict__ deg) {
  int i = blockIdx.x * blockDim.x + threadIdx.x;
  int stride = gridDim.x * blockDim.x;
  for (; i < NE; i += stride) atomicAdd(&deg[dst[i]], 1);
}

// ---------------------------------------------------------------- dinv = rsqrt(deg+1)
__global__ __launch_bounds__(256) void k_dinv(const int* __restrict__ deg,
                                              float* __restrict__ dinv) {
  int i = blockIdx.x * blockDim.x + threadIdx.x;
  if (i < NN) dinv[i] = rsqrtf((float)(deg[i] + 1));
}

// ---------------------------------------------------------------- h2 = (x @ Wc) * dinv[row]
// block 256 threads computes 64 rows x 128 cols; K staged in chunks of 32.
__global__ __launch_bounds__(256) void k_gemm1(const float* __restrict__ x,
                                               const float* __restrict__ W,
                                               const float* __restrict__ dinv,
                                               float* __restrict__ h2) {
  __shared__ float xs[64][33];
  __shared__ float ws[32][128];
  const int tid = threadIdx.x;
  const int row0 = blockIdx.x * 64;
  const int tm = tid >> 4, tn = tid & 15;
  float acc[4][8];
#pragma unroll
  for (int r = 0; r < 4; ++r)
#pragma unroll
    for (int c = 0; c < 8; ++c) acc[r][c] = 0.f;

  const int lr = tid >> 2;        // 0..63 (row within tile for x loads)
  const int lc = (tid & 3) * 8;   // 0,8,16,24

  for (int k0 = 0; k0 < INF_; k0 += 32) {
    // stage x tile [64][32]
    {
      int grow = row0 + lr;
      if (grow < NN) {
        const float4 v0 = *(const float4*)&x[(size_t)grow * INF_ + k0 + lc];
        const float4 v1 = *(const float4*)&x[(size_t)grow * INF_ + k0 + lc + 4];
        xs[lr][lc + 0] = v0.x; xs[lr][lc + 1] = v0.y;
        xs[lr][lc + 2] = v0.z; xs[lr][lc + 3] = v0.w;
        xs[lr][lc + 4] = v1.x; xs[lr][lc + 5] = v1.y;
        xs[lr][lc + 6] = v1.z; xs[lr][lc + 7] = v1.w;
      } else {
#pragma unroll
        for (int j = 0; j < 8; ++j) xs[lr][lc + j] = 0.f;
      }
    }
    // stage W tile [32][128] — contiguous 16KB starting at W + k0*128
    {
      float4* wsf = (float4*)&ws[0][0];
      const float4* Wg = (const float4*)&W[(size_t)k0 * HID];
#pragma unroll
      for (int v = 0; v < 4; ++v) wsf[v * 256 + tid] = Wg[v * 256 + tid];
    }
    __syncthreads();
#pragma unroll
    for (int k = 0; k < 32; ++k) {
      const float a0 = xs[tm * 4 + 0][k];
      const float a1 = xs[tm * 4 + 1][k];
      const float a2 = xs[tm * 4 + 2][k];
      const float a3 = xs[tm * 4 + 3][k];
      const float4 w0 = *(const float4*)&ws[k][tn * 8];
      const float4 w1 = *(const float4*)&ws[k][tn * 8 + 4];
      const float wv[8] = {w0.x, w0.y, w0.z, w0.w, w1.x, w1.y, w1.z, w1.w};
#pragma unroll
      for (int c = 0; c < 8; ++c) {
        acc[0][c] = fmaf(a0, wv[c], acc[0][c]);
        acc[1][c] = fmaf(a1, wv[c], acc[1][c]);
        acc[2][c] = fmaf(a2, wv[c], acc[2][c]);
        acc[3][c] = fmaf(a3, wv[c], acc[3][c]);
      }
    }
    __syncthreads();
  }
#pragma unroll
  for (int r = 0; r < 4; ++r) {
    const int grow = row0 + tm * 4 + r;
    if (grow < NN) {
      const float dv = dinv[grow];
      float4 o0, o1;
      o0.x = acc[r][0] * dv; o0.y = acc[r][1] * dv;
      o0.z = acc[r][2] * dv; o0.w = acc[r][3] * dv;
      o1.x = acc[r][4] * dv; o1.y = acc[r][5] * dv;
      o1.z = acc[r][6] * dv; o1.w = acc[r][7] * dv;
      *(float4*)&h2[(size_t)grow * HID + tn * 8] = o0;
      *(float4*)&h2[(size_t)grow * HID + tn * 8 + 4] = o1;
    }
  }
}

// ---------------------------------------------------------------- scatter-add: agg[dst] += h2[src]
// one 64-lane wave per edge; lane handles 2 channels (float2 = 8B/lane => 512B/row)
__global__ __launch_bounds__(256) void k_scatter(const int* __restrict__ src,
                                                 const int* __restrict__ dst,
                                                 const float* __restrict__ h2,
                                                 float* __restrict__ agg) {
  const int lane = threadIdx.x & 63;
  int wave = blockIdx.x * (blockDim.x >> 6) + (threadIdx.x >> 6);
  const int nw = gridDim.x * (blockDim.x >> 6);
  for (int e = wave; e < NE; e += nw) {
    const int s = src[e], d = dst[e];
    const float2 v = *(const float2*)&h2[(size_t)s * HID + lane * 2];
    float* p = &agg[(size_t)d * HID + lane * 2];
    unsafeAtomicAdd(p, v.x);
    unsafeAtomicAdd(p + 1, v.y);
  }
}

// ---------------------------------------------------------------- finalize:
// t = relu(dinv*(agg+h2) + b_conv); logits = t@Wl + bl; out = log_softmax(logits)
__global__ __launch_bounds__(128) void k_finalize(const float* __restrict__ agg,
                                                  const float* __restrict__ h2,
                                                  const float* __restrict__ dinv,
                                                  const float* __restrict__ bc,
                                                  const float* __restrict__ Wl,
                                                  const float* __restrict__ bl,
                                                  float* __restrict__ out) {
  __shared__ float sh[HID];
  __shared__ float part[8][OUTF];
  __shared__ float lg[OUTF];
  const int v = blockIdx.x;
  const int t = threadIdx.x;
  const float dv = dinv[v];
  float val = dv * (agg[(size_t)v * HID + t] + h2[(size_t)v * HID + t]) + bc[t];
  sh[t] = fmaxf(val, 0.f);
  __syncthreads();
  const int o = t & 15, pid = t >> 4;  // 8 partial groups of 16 channels
  float s = 0.f;
#pragma unroll
  for (int c = 0; c < 16; ++c) {
    const int cc = pid * 16 + c;
    s = fmaf(sh[cc], Wl[cc * OUTF + o], s);
  }
  part[pid][o] = s;
  __syncthreads();
  if (t < OUTF) {
    float sum = bl[t];
#pragma unroll
    for (int p = 0; p < 8; ++p) sum += part[p][t];
    lg[t] = sum;
  }
  __syncthreads();
  if (t < OUTF) {
    float m = -INFINITY;
#pragma unroll
    for (int i = 0; i < OUTF; ++i) m = fmaxf(m, lg[i]);
    float se = 0.f;
#pragma unroll
    for (int i = 0; i < OUTF; ++i) se += expf(lg[i] - m);
    out[(size_t)v * OUTF + t] = lg[t] - m - logf(se);
  }
}

// ---------------------------------------------------------------- launch
extern "C" void kernel_launch(void* const* d_in, const int* in_sizes, int n_in,
                              void* d_out, int out_size, void* d_ws, size_t ws_size,
                              hipStream_t stream) {
  const float* x  = (const float*)d_in[0];
  const int*   ei = (const int*)d_in[1];   // [2][NE], int32 (JAX x64 disabled)
  const float* Wc = (const float*)d_in[2]; // [256][128]
  const float* bc = (const float*)d_in[3]; // [128] (zeros)
  const float* Wl = (const float*)d_in[4]; // [128][16]
  const float* bl = (const float*)d_in[5]; // [16]
  float* out = (float*)d_out;

  float* agg  = (float*)d_ws;                    // NN*128 f32 = 51.2 MB
  float* h2   = agg + (size_t)NN * HID;          // NN*128 f32 = 51.2 MB
  float* dinv = h2 + (size_t)NN * HID;           // NN f32
  int*   deg  = (int*)(dinv + NN);               // NN i32

  const int* srcv = ei;        // edge_index[0]
  const int* dstv = ei + NE;   // edge_index[1]

  hipMemsetAsync(agg, 0, (size_t)NN * HID * sizeof(float), stream);
  hipMemsetAsync(deg, 0, (size_t)NN * sizeof(int), stream);

  k_deg<<<2048, 256, 0, stream>>>(dstv, deg);
  k_dinv<<<(NN + 255) / 256, 256, 0, stream>>>(deg, dinv);
  k_gemm1<<<(NN + 63) / 64, 256, 0, stream>>>(x, Wc, dinv, h2);
  k_scatter<<<2048, 256, 0, stream>>>(srcv, dstv, h2, agg);
  k_finalize<<<NN, 128, 0, stream>>>(agg, h2, dinv, bc, Wl, bl, out);
}

// Round 2
// 457.434 us; speedup vs baseline: 3.3655x; 3.3655x over previous
//
#include <hip/hip_runtime.h>
#include <math.h>

#define NN    100000
#define INF_  256
#define HID   128
#define OUTF  16
#define NE    1600000
#define SCAN_CH 1024
#define NBLK ((NN + SCAN_CH - 1) / SCAN_CH)   // 98

// ---------------------------------------------------------------- degree (int atomics, cursor fits L2)
__global__ __launch_bounds__(256) void k_deg(const int* __restrict__ dst,
                                             int* __restrict__ deg) {
  int i = blockIdx.x * blockDim.x + threadIdx.x;
  const int stride = gridDim.x * blockDim.x;
  for (; i < NE; i += stride) atomicAdd(&deg[dst[i]], 1);
}

// ---------------------------------------------------------------- dinv = rsqrt(deg+1)
__global__ __launch_bounds__(256) void k_dinv(const int* __restrict__ deg,
                                              float* __restrict__ dinv) {
  int i = blockIdx.x * blockDim.x + threadIdx.x;
  if (i < NN) dinv[i] = rsqrtf((float)(deg[i] + 1));
}

// ---------------------------------------------------------------- h2 = (x @ Wc) * dinv[row]
__global__ __launch_bounds__(256) void k_gemm1(const float* __restrict__ x,
                                               const float* __restrict__ W,
                                               const float* __restrict__ dinv,
                                               float* __restrict__ h2) {
  __shared__ float xs[64][33];
  __shared__ float ws[32][128];
  const int tid = threadIdx.x;
  const int row0 = blockIdx.x * 64;
  const int tm = tid >> 4, tn = tid & 15;
  float acc[4][8];
#pragma unroll
  for (int r = 0; r < 4; ++r)
#pragma unroll
    for (int c = 0; c < 8; ++c) acc[r][c] = 0.f;

  const int lr = tid >> 2;
  const int lc = (tid & 3) * 8;

  for (int k0 = 0; k0 < INF_; k0 += 32) {
    {
      int grow = row0 + lr;
      if (grow < NN) {
        const float4 v0 = *(const float4*)&x[(size_t)grow * INF_ + k0 + lc];
        const float4 v1 = *(const float4*)&x[(size_t)grow * INF_ + k0 + lc + 4];
        xs[lr][lc + 0] = v0.x; xs[lr][lc + 1] = v0.y;
        xs[lr][lc + 2] = v0.z; xs[lr][lc + 3] = v0.w;
        xs[lr][lc + 4] = v1.x; xs[lr][lc + 5] = v1.y;
        xs[lr][lc + 6] = v1.z; xs[lr][lc + 7] = v1.w;
      } else {
#pragma unroll
        for (int j = 0; j < 8; ++j) xs[lr][lc + j] = 0.f;
      }
    }
    {
      float4* wsf = (float4*)&ws[0][0];
      const float4* Wg = (const float4*)&W[(size_t)k0 * HID];
#pragma unroll
      for (int v = 0; v < 4; ++v) wsf[v * 256 + tid] = Wg[v * 256 + tid];
    }
    __syncthreads();
#pragma unroll
    for (int k = 0; k < 32; ++k) {
      const float a0 = xs[tm * 4 + 0][k];
      const float a1 = xs[tm * 4 + 1][k];
      const float a2 = xs[tm * 4 + 2][k];
      const float a3 = xs[tm * 4 + 3][k];
      const float4 w0 = *(const float4*)&ws[k][tn * 8];
      const float4 w1 = *(const float4*)&ws[k][tn * 8 + 4];
      const float wv[8] = {w0.x, w0.y, w0.z, w0.w, w1.x, w1.y, w1.z, w1.w};
#pragma unroll
      for (int c = 0; c < 8; ++c) {
        acc[0][c] = fmaf(a0, wv[c], acc[0][c]);
        acc[1][c] = fmaf(a1, wv[c], acc[1][c]);
        acc[2][c] = fmaf(a2, wv[c], acc[2][c]);
        acc[3][c] = fmaf(a3, wv[c], acc[3][c]);
      }
    }
    __syncthreads();
  }
#pragma unroll
  for (int r = 0; r < 4; ++r) {
    const int grow = row0 + tm * 4 + r;
    if (grow < NN) {
      const float dv = dinv[grow];
      float4 o0, o1;
      o0.x = acc[r][0] * dv; o0.y = acc[r][1] * dv;
      o0.z = acc[r][2] * dv; o0.w = acc[r][3] * dv;
      o1.x = acc[r][4] * dv; o1.y = acc[r][5] * dv;
      o1.z = acc[r][6] * dv; o1.w = acc[r][7] * dv;
      *(float4*)&h2[(size_t)grow * HID + tn * 8] = o0;
      *(float4*)&h2[(size_t)grow * HID + tn * 8 + 4] = o1;
    }
  }
}

// ---------------------------------------------------------------- scan step 1: per-block sums (1024 elems/block)
__global__ __launch_bounds__(256) void k_bsum(const int* __restrict__ deg,
                                              int* __restrict__ bsum) {
  __shared__ int sh[256];
  const int b = blockIdx.x, t = threadIdx.x;
  const int base = b * SCAN_CH + t * 4;
  int s = 0;
#pragma unroll
  for (int j = 0; j < 4; ++j) {
    const int i = base + j;
    if (i < NN) s += deg[i];
  }
  sh[t] = s;
  __syncthreads();
  for (int off = 128; off; off >>= 1) {
    if (t < off) sh[t] += sh[t + off];
    __syncthreads();
  }
  if (t == 0) bsum[b] = sh[0];
}

// ---------------------------------------------------------------- scan step 2: serial scan of 98 block sums
__global__ void k_scanb(const int* __restrict__ bsum, int* __restrict__ bbase,
                        int* __restrict__ rowptr) {
  if (threadIdx.x == 0 && blockIdx.x == 0) {
    int run = 0;
    for (int i = 0; i < NBLK; ++i) { bbase[i] = run; run += bsum[i]; }
    rowptr[NN] = run;  // == NE
  }
}

// ---------------------------------------------------------------- scan step 3: rowptr = exclusive scan
__global__ __launch_bounds__(256) void k_fillptr(const int* __restrict__ deg,
                                                 const int* __restrict__ bbase,
                                                 int* __restrict__ rowptr) {
  __shared__ int sh[256];
  const int b = blockIdx.x, t = threadIdx.x;
  const int base = b * SCAN_CH + t * 4;
  int v[4];
  int s = 0;
#pragma unroll
  for (int j = 0; j < 4; ++j) {
    const int i = base + j;
    v[j] = (i < NN) ? deg[i] : 0;
    s += v[j];
  }
  sh[t] = s;
  __syncthreads();
  for (int off = 1; off < 256; off <<= 1) {
    int tmp = (t >= off) ? sh[t - off] : 0;
    __syncthreads();
    sh[t] += tmp;
    __syncthreads();
  }
  int run = bbase[b] + sh[t] - s;  // exclusive prefix for this thread's 4 elems
#pragma unroll
  for (int j = 0; j < 4; ++j) {
    const int i = base + j;
    if (i < NN) rowptr[i] = run;
    run += v[j];
  }
}

// ---------------------------------------------------------------- cursor = rowptr copy
__global__ __launch_bounds__(256) void k_copycur(const int* __restrict__ rowptr,
                                                 int* __restrict__ cursor) {
  const int i = blockIdx.x * blockDim.x + threadIdx.x;
  if (i < NN) cursor[i] = rowptr[i];
}

// ---------------------------------------------------------------- counting-sort fill: csr[pos] = src, grouped by dst
__global__ __launch_bounds__(256) void k_fill(const int* __restrict__ src,
                                              const int* __restrict__ dst,
                                              int* __restrict__ cursor,
                                              int* __restrict__ csr) {
  int i = blockIdx.x * blockDim.x + threadIdx.x;
  const int stride = gridDim.x * blockDim.x;
  for (; i < NE; i += stride) {
    const int pos = atomicAdd(&cursor[dst[i]], 1);
    csr[pos] = src[i];
  }
}

// ---------------------------------------------------------------- gather + finalize fused
// one 64-lane wave per node; lane owns channels {2*lane, 2*lane+1}
__global__ __launch_bounds__(256) void k_gather(const int* __restrict__ rowptr,
                                                const int* __restrict__ csr,
                                                const float* __restrict__ h2,
                                                const float* __restrict__ dinv,
                                                const float* __restrict__ bc,
                                                const float* __restrict__ Wl,
                                                const float* __restrict__ bl,
                                                float* __restrict__ out) {
  const int wid = blockIdx.x * 4 + (threadIdx.x >> 6);
  const int lane = threadIdx.x & 63;
  if (wid >= NN) return;
  const int v = wid;
  const int rp = rowptr[v], re = rowptr[v + 1];
  const int c0 = lane * 2;

  float2 a0 = {0.f, 0.f}, a1 = {0.f, 0.f};
  for (int base = rp; base < re; base += 64) {
    const int n = min(64, re - base);
    int idx = 0;
    if (base + lane < re) idx = csr[base + lane];
    int j = 0;
    for (; j + 1 < n; j += 2) {
      const int s0 = __shfl(idx, j);
      const int s1 = __shfl(idx, j + 1);
      const float2 m0 = *(const float2*)&h2[(size_t)s0 * HID + c0];
      const float2 m1 = *(const float2*)&h2[(size_t)s1 * HID + c0];
      a0.x += m0.x; a0.y += m0.y;
      a1.x += m1.x; a1.y += m1.y;
    }
    if (j < n) {
      const int s0 = __shfl(idx, j);
      const float2 m0 = *(const float2*)&h2[(size_t)s0 * HID + c0];
      a0.x += m0.x; a0.y += m0.y;
    }
  }

  const float dv = dinv[v];
  const float2 hs = *(const float2*)&h2[(size_t)v * HID + c0];
  const float t0 = fmaxf(fmaf(dv, a0.x + a1.x + hs.x, bc[c0 + 0]), 0.f);
  const float t1 = fmaxf(fmaf(dv, a0.y + a1.y + hs.y, bc[c0 + 1]), 0.f);

  // partial logits: p[o] = t0*Wl[c0][o] + t1*Wl[c0+1][o]
  float p[OUTF];
  {
    const float4* wa = (const float4*)&Wl[(size_t)c0 * OUTF];
    const float4* wb = (const float4*)&Wl[(size_t)(c0 + 1) * OUTF];
#pragma unroll
    for (int q = 0; q < 4; ++q) {
      const float4 a = wa[q], b = wb[q];
      p[q * 4 + 0] = t0 * a.x + t1 * b.x;
      p[q * 4 + 1] = t0 * a.y + t1 * b.y;
      p[q * 4 + 2] = t0 * a.z + t1 * b.z;
      p[q * 4 + 3] = t0 * a.w + t1 * b.w;
    }
  }
  // butterfly reduce across the wave
#pragma unroll
  for (int off = 32; off; off >>= 1)
#pragma unroll
    for (int q = 0; q < OUTF; ++q) p[q] += __shfl_xor(p[q], off);

  if (lane == 0) {
    float lg[OUTF];
    float m = -INFINITY;
#pragma unroll
    for (int q = 0; q < OUTF; ++q) { lg[q] = p[q] + bl[q]; m = fmaxf(m, lg[q]); }
    float se = 0.f;
#pragma unroll
    for (int q = 0; q < OUTF; ++q) se += expf(lg[q] - m);
    const float lse = m + logf(se);
    float4 o[4];
#pragma unroll
    for (int q = 0; q < OUTF; ++q) ((float*)o)[q] = lg[q] - lse;
    float4* op = (float4*)&out[(size_t)v * OUTF];
#pragma unroll
    for (int q = 0; q < 4; ++q) op[q] = o[q];
  }
}

// ---------------------------------------------------------------- launch
extern "C" void kernel_launch(void* const* d_in, const int* in_sizes, int n_in,
                              void* d_out, int out_size, void* d_ws, size_t ws_size,
                              hipStream_t stream) {
  const float* x  = (const float*)d_in[0];
  const int*   ei = (const int*)d_in[1];
  const float* Wc = (const float*)d_in[2];
  const float* bc = (const float*)d_in[3];
  const float* Wl = (const float*)d_in[4];
  const float* bl = (const float*)d_in[5];
  float* out = (float*)d_out;

  float* h2     = (float*)d_ws;                  // NN*HID f32 = 51.2 MB
  float* dinv   = h2 + (size_t)NN * HID;         // NN f32
  int*   deg    = (int*)(dinv + NN);             // NN i32
  int*   rowptr = deg + NN;                      // NN+1 i32
  int*   cursor = rowptr + NN + 1;               // NN i32
  int*   bsum   = cursor + NN;                   // NBLK i32
  int*   bbase  = bsum + NBLK;                   // NBLK i32
  int*   csr    = bbase + NBLK;                  // NE i32 = 6.4 MB

  const int* srcv = ei;
  const int* dstv = ei + NE;

  hipMemsetAsync(deg, 0, (size_t)NN * sizeof(int), stream);

  k_deg<<<2048, 256, 0, stream>>>(dstv, deg);
  k_dinv<<<(NN + 255) / 256, 256, 0, stream>>>(deg, dinv);
  k_gemm1<<<(NN + 63) / 64, 256, 0, stream>>>(x, Wc, dinv, h2);
  k_bsum<<<NBLK, 256, 0, stream>>>(deg, bsum);
  k_scanb<<<1, 64, 0, stream>>>(bsum, bbase, rowptr);
  k_fillptr<<<NBLK, 256, 0, stream>>>(deg, bbase, rowptr);
  k_copycur<<<(NN + 255) / 256, 256, 0, stream>>>(rowptr, cursor);
  k_fill<<<2048, 256, 0, stream>>>(srcv, dstv, cursor, csr);
  k_gather<<<(NN + 3) / 4, 256, 0, stream>>>(rowptr, csr, h2, dinv, bc, Wl, bl, out);
}

// Round 3
// 355.734 us; speedup vs baseline: 4.3277x; 1.2859x over previous
//
#include <hip/hip_runtime.h>
#include <math.h>

#define NN    100000
#define INF_  256
#define HID   128
#define OUTF  16
#define NE    1600000
#define SCAN_CH 1024
#define NBLK ((NN + SCAN_CH - 1) / SCAN_CH)   // 98

typedef __attribute__((ext_vector_type(4))) float f32x4;
typedef __attribute__((ext_vector_type(8))) short bf16x8;

__device__ inline unsigned short f32_to_bf16(float f) {
  union { float f; unsigned int u; } v; v.f = f;
  unsigned int x = v.u;
  unsigned int r = x + 0x7fffu + ((x >> 16) & 1u);  // RNE
  return (unsigned short)(r >> 16);
}
__device__ inline float bf16lo_to_f32(unsigned int u) {
  union { unsigned int u; float f; } v; v.u = u << 16; return v.f;
}
__device__ inline float bf16hi_to_f32(unsigned int u) {
  union { unsigned int u; float f; } v; v.u = u & 0xffff0000u; return v.f;
}

// ---------------------------------------------------------------- degree
__global__ __launch_bounds__(256) void k_deg(const int* __restrict__ dst,
                                             int* __restrict__ deg) {
  int i = blockIdx.x * blockDim.x + threadIdx.x;
  const int stride = gridDim.x * blockDim.x;
  for (; i < NE; i += stride) atomicAdd(&deg[dst[i]], 1);
}

// ---------------------------------------------------------------- dinv = rsqrt(deg+1)
__global__ __launch_bounds__(256) void k_dinv(const int* __restrict__ deg,
                                              float* __restrict__ dinv) {
  int i = blockIdx.x * blockDim.x + threadIdx.x;
  if (i < NN) dinv[i] = rsqrtf((float)(deg[i] + 1));
}

// ---------------------------------------------------------------- W prep: bf16, transposed [n][k], pre-swizzled 16B chunks
// layout: for K-step s (k0=32s), col n, local k-chunk c (8 bf16):
//   chunk_index = s*512 + n*4 + (c ^ (n&3)); element j at WTs[chunk*8 + j]
__global__ __launch_bounds__(256) void k_wprep(const float* __restrict__ W,
                                               unsigned short* __restrict__ WTs) {
  const int i = blockIdx.x * 256 + threadIdx.x;
  if (i >= INF_ * HID) return;
  const int k = i >> 7, n = i & 127;
  const int s = k >> 5, c = (k >> 3) & 3, j = k & 7;
  const int chunk = s * 512 + n * 4 + (c ^ (n & 3));
  WTs[chunk * 8 + j] = f32_to_bf16(W[i]);
}

// ---------------------------------------------------------------- MFMA GEMM: h2b = bf16( (x @ Wc) * dinv[row] )
// block: 256 thr (4 waves), tile 128 rows x 128 cols, BK=32, 8 K-steps.
__global__ __launch_bounds__(256) void k_gemm(const float* __restrict__ x,
                                              const unsigned short* __restrict__ WTs,
                                              const float* __restrict__ dinv,
                                              unsigned short* __restrict__ h2b) {
  __shared__ unsigned short xs[128 * 32];  // A tile, swizzled 16B chunks
  __shared__ unsigned short ws[128 * 32];  // B tile [n][k], swizzled
  const int tid = threadIdx.x;
  const int wave = tid >> 6, lane = tid & 63;
  const int l15 = lane & 15, l4 = lane >> 4;
  const int row0 = blockIdx.x * 128;

  f32x4 acc[2][8];
#pragma unroll
  for (int rb = 0; rb < 2; ++rb)
#pragma unroll
    for (int n = 0; n < 8; ++n) { acc[rb][n].x = 0.f; acc[rb][n].y = 0.f; acc[rb][n].z = 0.f; acc[rb][n].w = 0.f; }

  for (int s = 0; s < 8; ++s) {
    // --- stage A: 512 chunks (row 0..127, kc 0..3), 2 per thread, f32->bf16
#pragma unroll
    for (int p = 0; p < 2; ++p) {
      const int c = tid + p * 256;
      const int row = c >> 2, kc = c & 3;
      const int grow = row0 + row;
      unsigned short tmp[8];
      if (grow < NN) {
        const float4 v0 = *(const float4*)&x[(size_t)grow * INF_ + s * 32 + kc * 8];
        const float4 v1 = *(const float4*)&x[(size_t)grow * INF_ + s * 32 + kc * 8 + 4];
        tmp[0] = f32_to_bf16(v0.x); tmp[1] = f32_to_bf16(v0.y);
        tmp[2] = f32_to_bf16(v0.z); tmp[3] = f32_to_bf16(v0.w);
        tmp[4] = f32_to_bf16(v1.x); tmp[5] = f32_to_bf16(v1.y);
        tmp[6] = f32_to_bf16(v1.z); tmp[7] = f32_to_bf16(v1.w);
      } else {
#pragma unroll
        for (int j = 0; j < 8; ++j) tmp[j] = 0;
      }
      const int phys = kc ^ (row & 3);
      *(bf16x8*)&xs[(row * 4 + phys) * 8] = *(bf16x8*)tmp;
    }
    // --- stage B: linear 16B copies from pre-swizzled WTs (L2-resident)
#pragma unroll
    for (int p = 0; p < 2; ++p) {
      const int c = tid + p * 256;
      *(bf16x8*)&ws[c * 8] = *(const bf16x8*)&WTs[(s * 512 + c) * 8];
    }
    __syncthreads();
    // --- compute
    bf16x8 af[2];
#pragma unroll
    for (int rb = 0; rb < 2; ++rb) {
      const int row = wave * 32 + rb * 16 + l15;
      af[rb] = *(const bf16x8*)&xs[(row * 4 + (l4 ^ (row & 3))) * 8];
    }
#pragma unroll
    for (int n = 0; n < 8; ++n) {
      const int col = n * 16 + l15;
      const bf16x8 bf = *(const bf16x8*)&ws[(col * 4 + (l4 ^ (col & 3))) * 8];
      acc[0][n] = __builtin_amdgcn_mfma_f32_16x16x32_bf16(af[0], bf, acc[0][n], 0, 0, 0);
      acc[1][n] = __builtin_amdgcn_mfma_f32_16x16x32_bf16(af[1], bf, acc[1][n], 0, 0, 0);
    }
    __syncthreads();
  }
  // --- epilogue: scale by dinv[row], store bf16
#pragma unroll
  for (int rb = 0; rb < 2; ++rb) {
#pragma unroll
    for (int r = 0; r < 4; ++r) {
      const int rowg = row0 + wave * 32 + rb * 16 + l4 * 4 + r;
      if (rowg < NN) {
        const float dv = dinv[rowg];
#pragma unroll
        for (int n = 0; n < 8; ++n)
          h2b[(size_t)rowg * HID + n * 16 + l15] = f32_to_bf16(acc[rb][n][r] * dv);
      }
    }
  }
}

// ---------------------------------------------------------------- scan step 1: per-block sums
__global__ __launch_bounds__(256) void k_bsum(const int* __restrict__ deg,
                                              int* __restrict__ bsum) {
  __shared__ int sh[256];
  const int b = blockIdx.x, t = threadIdx.x;
  const int base = b * SCAN_CH + t * 4;
  int s = 0;
#pragma unroll
  for (int j = 0; j < 4; ++j) {
    const int i = base + j;
    if (i < NN) s += deg[i];
  }
  sh[t] = s;
  __syncthreads();
  for (int off = 128; off; off >>= 1) {
    if (t < off) sh[t] += sh[t + off];
    __syncthreads();
  }
  if (t == 0) bsum[b] = sh[0];
}

// ---------------------------------------------------------------- scan step 2: serial scan of block sums
__global__ void k_scanb(const int* __restrict__ bsum, int* __restrict__ bbase,
                        int* __restrict__ rowptr) {
  if (threadIdx.x == 0 && blockIdx.x == 0) {
    int run = 0;
    for (int i = 0; i < NBLK; ++i) { bbase[i] = run; run += bsum[i]; }
    rowptr[NN] = run;
  }
}

// ---------------------------------------------------------------- scan step 3: rowptr + cursor
__global__ __launch_bounds__(256) void k_fillptr(const int* __restrict__ deg,
                                                 const int* __restrict__ bbase,
                                                 int* __restrict__ rowptr,
                                                 int* __restrict__ cursor) {
  __shared__ int sh[256];
  const int b = blockIdx.x, t = threadIdx.x;
  const int base = b * SCAN_CH + t * 4;
  int v[4];
  int s = 0;
#pragma unroll
  for (int j = 0; j < 4; ++j) {
    const int i = base + j;
    v[j] = (i < NN) ? deg[i] : 0;
    s += v[j];
  }
  sh[t] = s;
  __syncthreads();
  for (int off = 1; off < 256; off <<= 1) {
    int tmp = (t >= off) ? sh[t - off] : 0;
    __syncthreads();
    sh[t] += tmp;
    __syncthreads();
  }
  int run = bbase[b] + sh[t] - s;
#pragma unroll
  for (int j = 0; j < 4; ++j) {
    const int i = base + j;
    if (i < NN) { rowptr[i] = run; cursor[i] = run; }
    run += v[j];
  }
}

// ---------------------------------------------------------------- counting-sort fill
__global__ __launch_bounds__(256) void k_fill(const int* __restrict__ src,
                                              const int* __restrict__ dst,
                                              int* __restrict__ cursor,
                                              int* __restrict__ csr) {
  int i = blockIdx.x * blockDim.x + threadIdx.x;
  const int stride = gridDim.x * blockDim.x;
  for (; i < NE; i += stride) {
    const int pos = atomicAdd(&cursor[dst[i]], 1);
    csr[pos] = src[i];
  }
}

// ---------------------------------------------------------------- gather + finalize fused
// one wave per node; lane owns channels {2*lane, 2*lane+1}; csr via scalar loads
__global__ __launch_bounds__(256) void k_gather(const int* __restrict__ rowptr,
                                                const int* __restrict__ csr,
                                                const unsigned short* __restrict__ h2b,
                                                const float* __restrict__ dinv,
                                                const float* __restrict__ bc,
                                                const float* __restrict__ Wl,
                                                const float* __restrict__ bl,
                                                float* __restrict__ out) {
  const int wid = blockIdx.x * 4 + (threadIdx.x >> 6);
  const int lane = threadIdx.x & 63;
  if (wid >= NN) return;
  const int v  = __builtin_amdgcn_readfirstlane(wid);
  const int rp = __builtin_amdgcn_readfirstlane(rowptr[v]);
  const int re = __builtin_amdgcn_readfirstlane(rowptr[v + 1]);
  const int c0 = lane * 2;

  float ax0 = 0.f, ay0 = 0.f, ax1 = 0.f, ay1 = 0.f;
  float ax2 = 0.f, ay2 = 0.f, ax3 = 0.f, ay3 = 0.f;
  int j = rp;
  for (; j + 4 <= re; j += 4) {
    const int s0 = csr[j], s1 = csr[j + 1], s2 = csr[j + 2], s3 = csr[j + 3];
    const unsigned int u0 = *(const unsigned int*)&h2b[(size_t)s0 * HID + c0];
    const unsigned int u1 = *(const unsigned int*)&h2b[(size_t)s1 * HID + c0];
    const unsigned int u2 = *(const unsigned int*)&h2b[(size_t)s2 * HID + c0];
    const unsigned int u3 = *(const unsigned int*)&h2b[(size_t)s3 * HID + c0];
    ax0 += bf16lo_to_f32(u0); ay0 += bf16hi_to_f32(u0);
    ax1 += bf16lo_to_f32(u1); ay1 += bf16hi_to_f32(u1);
    ax2 += bf16lo_to_f32(u2); ay2 += bf16hi_to_f32(u2);
    ax3 += bf16lo_to_f32(u3); ay3 += bf16hi_to_f32(u3);
  }
  for (; j < re; ++j) {
    const int s0 = csr[j];
    const unsigned int u0 = *(const unsigned int*)&h2b[(size_t)s0 * HID + c0];
    ax0 += bf16lo_to_f32(u0); ay0 += bf16hi_to_f32(u0);
  }
  const float sx = (ax0 + ax1) + (ax2 + ax3);
  const float sy = (ay0 + ay1) + (ay2 + ay3);

  const float dv = dinv[v];
  const unsigned int us = *(const unsigned int*)&h2b[(size_t)v * HID + c0];
  const float2 bcv = *(const float2*)&bc[c0];
  const float t0 = fmaxf(fmaf(dv, sx + bf16lo_to_f32(us), bcv.x), 0.f);
  const float t1 = fmaxf(fmaf(dv, sy + bf16hi_to_f32(us), bcv.y), 0.f);

  // partial logits p[16] = t0*Wl[c0][:] + t1*Wl[c0+1][:]
  float p[OUTF];
  {
    const float4* wa = (const float4*)&Wl[(size_t)c0 * OUTF];
    const float4* wb = (const float4*)&Wl[(size_t)(c0 + 1) * OUTF];
#pragma unroll
    for (int q = 0; q < 4; ++q) {
      const float4 a = wa[q], b = wb[q];
      p[q * 4 + 0] = t0 * a.x + t1 * b.x;
      p[q * 4 + 1] = t0 * a.y + t1 * b.y;
      p[q * 4 + 2] = t0 * a.z + t1 * b.z;
      p[q * 4 + 3] = t0 * a.w + t1 * b.w;
    }
  }
  // halving tree reduce: after this, lane L holds output o = (L>>2)&15
  const bool u5 = lane & 32;
  float q8[8];
#pragma unroll
  for (int i = 0; i < 8; ++i) {
    const float send = u5 ? p[i] : p[i + 8];
    const float recv = __shfl_xor(send, 32);
    q8[i] = (u5 ? p[i + 8] : p[i]) + recv;
  }
  const bool u4 = lane & 16;
  float q4[4];
#pragma unroll
  for (int i = 0; i < 4; ++i) {
    const float send = u4 ? q8[i] : q8[i + 4];
    const float recv = __shfl_xor(send, 16);
    q4[i] = (u4 ? q8[i + 4] : q8[i]) + recv;
  }
  const bool u3 = lane & 8;
  float q2[2];
#pragma unroll
  for (int i = 0; i < 2; ++i) {
    const float send = u3 ? q2[0] * 0.f + q4[i] : q4[i + 2];  // keep simple forms
    const float recv = __shfl_xor(u3 ? q4[i] : q4[i + 2], 8);
    q2[i] = (u3 ? q4[i + 2] : q4[i]) + recv;
  }
  const bool u2 = lane & 4;
  {
    const float send = u2 ? q2[0] : q2[1];
    const float recv = __shfl_xor(send, 4);
    float t = (u2 ? q2[1] : q2[0]) + recv;
    t += __shfl_xor(t, 2);
    t += __shfl_xor(t, 1);
    const int o = (lane >> 2) & 15;
    const float lg = t + bl[o];
    // cooperative softmax over the 16 outputs (lanes differ in bits 2..5)
    float m = lg;
    m = fmaxf(m, __shfl_xor(m, 4));
    m = fmaxf(m, __shfl_xor(m, 8));
    m = fmaxf(m, __shfl_xor(m, 16));
    m = fmaxf(m, __shfl_xor(m, 32));
    float e = expf(lg - m);
    float se = e;
    se += __shfl_xor(se, 4);
    se += __shfl_xor(se, 8);
    se += __shfl_xor(se, 16);
    se += __shfl_xor(se, 32);
    if ((lane & 3) == 0) out[(size_t)v * OUTF + o] = lg - m - logf(se);
  }
}

// ---------------------------------------------------------------- launch
extern "C" void kernel_launch(void* const* d_in, const int* in_sizes, int n_in,
                              void* d_out, int out_size, void* d_ws, size_t ws_size,
                              hipStream_t stream) {
  const float* x  = (const float*)d_in[0];
  const int*   ei = (const int*)d_in[1];
  const float* Wc = (const float*)d_in[2];
  const float* bc = (const float*)d_in[3];
  const float* Wl = (const float*)d_in[4];
  const float* bl = (const float*)d_in[5];
  float* out = (float*)d_out;

  unsigned short* h2b = (unsigned short*)d_ws;            // NN*HID bf16 = 25.6 MB
  unsigned short* WTs = h2b + (size_t)NN * HID;           // 32768 bf16 (64 KB)
  float* dinv   = (float*)(WTs + (size_t)INF_ * HID);     // NN f32
  int*   deg    = (int*)(dinv + NN);                      // NN
  int*   rowptr = deg + NN;                               // NN+1
  int*   cursor = rowptr + NN + 1;                        // NN
  int*   bsum   = cursor + NN;                            // NBLK
  int*   bbase  = bsum + NBLK;                            // NBLK
  int*   csr    = bbase + NBLK;                           // NE

  const int* srcv = ei;
  const int* dstv = ei + NE;

  hipMemsetAsync(deg, 0, (size_t)NN * sizeof(int), stream);

  k_deg<<<2048, 256, 0, stream>>>(dstv, deg);
  k_dinv<<<(NN + 255) / 256, 256, 0, stream>>>(deg, dinv);
  k_wprep<<<(INF_ * HID + 255) / 256, 256, 0, stream>>>(Wc, WTs);
  k_gemm<<<(NN + 127) / 128, 256, 0, stream>>>(x, WTs, dinv, h2b);
  k_bsum<<<NBLK, 256, 0, stream>>>(deg, bsum);
  k_scanb<<<1, 64, 0, stream>>>(bsum, bbase, rowptr);
  k_fillptr<<<NBLK, 256, 0, stream>>>(deg, bbase, rowptr, cursor);
  k_fill<<<2048, 256, 0, stream>>>(srcv, dstv, cursor, csr);
  k_gather<<<(NN + 3) / 4, 256, 0, stream>>>(rowptr, csr, h2b, dinv, bc, Wl, bl, out);
}